// Round 2
// baseline (391.325 us; speedup 1.0000x reference)
//
#include <hip/hip_runtime.h>

#define NROWS 32768
#define FDIM  2048
#define CDIM  64
#define BM    64
#define BK    32
#define SA    40   // padded LDS row stride in fp16 elements (80B rows, 16B-aligned frags)

#define EPS_R  1e-6f
#define XSCALE 256.0f
#define WSCALE 1024.0f
#define DESCALE (2.0f / (XSCALE * WSCALE))

typedef __attribute__((ext_vector_type(8))) _Float16 half8;
typedef __attribute__((ext_vector_type(4))) float    f32x4;

__device__ __forceinline__ unsigned packh(_Float16 a, _Float16 b) {
    return (unsigned)__builtin_bit_cast(unsigned short, a) |
           ((unsigned)__builtin_bit_cast(unsigned short, b) << 16);
}

// RNE two-term fp16 split: a = hi + lo with |err| <= 2^-22|a|
__device__ __forceinline__ void split2(float a, float b, unsigned& hi, unsigned& lo) {
    _Float16 ha = (_Float16)a, hb = (_Float16)b;
    _Float16 la = (_Float16)(a - (float)ha), lb = (_Float16)(b - (float)hb);
    hi = packh(ha, hb);
    lo = packh(la, lb);
}

// ---- prep: split (W*rc)*WSCALE into fp16 hi/lo, compute w_sq, once per call ----
__global__ __launch_bounds__(256) void gmlvq_prep(
    const float* __restrict__ W, const float* __restrict__ r,
    unsigned short* __restrict__ Bh, unsigned short* __restrict__ Bl,
    float* __restrict__ wsq) {
    const int c = blockIdx.x;
    const int tid = threadIdx.x;
    const int f0 = tid * 8;                       // 256*8 = 2048 exactly

    const float* Wp = W + (size_t)c * FDIM + f0;
    float4 w0 = *(const float4*)Wp;
    float4 w1 = *(const float4*)(Wp + 4);
    float4 r0 = *(const float4*)(r + f0);
    float4 r1 = *(const float4*)(r + f0 + 4);
    r0.x = fmaxf(r0.x, EPS_R); r0.y = fmaxf(r0.y, EPS_R);
    r0.z = fmaxf(r0.z, EPS_R); r0.w = fmaxf(r0.w, EPS_R);
    r1.x = fmaxf(r1.x, EPS_R); r1.y = fmaxf(r1.y, EPS_R);
    r1.z = fmaxf(r1.z, EPS_R); r1.w = fmaxf(r1.w, EPS_R);

    float rw0 = r0.x * w0.x, rw1 = r0.y * w0.y, rw2 = r0.z * w0.z, rw3 = r0.w * w0.w;
    float rw4 = r1.x * w1.x, rw5 = r1.y * w1.y, rw6 = r1.z * w1.z, rw7 = r1.w * w1.w;

    float part = rw0 * w0.x + rw1 * w0.y + rw2 * w0.z + rw3 * w0.w
               + rw4 * w1.x + rw5 * w1.y + rw6 * w1.z + rw7 * w1.w;

    unsigned h01, l01, h23, l23, h45, l45, h67, l67;
    split2(rw0 * WSCALE, rw1 * WSCALE, h01, l01);
    split2(rw2 * WSCALE, rw3 * WSCALE, h23, l23);
    split2(rw4 * WSCALE, rw5 * WSCALE, h45, l45);
    split2(rw6 * WSCALE, rw7 * WSCALE, h67, l67);

    *(uint4*)(Bh + (size_t)c * FDIM + f0) = make_uint4(h01, h23, h45, h67);
    *(uint4*)(Bl + (size_t)c * FDIM + f0) = make_uint4(l01, l23, l45, l67);

    // block reduction of w_sq
#pragma unroll
    for (int m = 32; m; m >>= 1) part += __shfl_xor(part, m);
    __shared__ float red[4];
    if ((tid & 63) == 0) red[tid >> 6] = part;
    __syncthreads();
    if (tid == 0) wsq[c] = (red[0] + red[1]) + (red[2] + red[3]);
}

// ---- main: stream X, split to fp16 hi/lo, 3-product MFMA GEMM, fused epilogue ----
__global__ __launch_bounds__(256, 2) void gmlvq_main(
    const float* __restrict__ X, const float* __restrict__ r,
    const unsigned short* __restrict__ Bh, const unsigned short* __restrict__ Bl,
    const float* __restrict__ wsq_g,
    float* __restrict__ dists, float* __restrict__ preds) {

    __shared__ unsigned short lds_ah[BM * SA], lds_al[BM * SA];
    __shared__ unsigned short lds_bh[CDIM * SA], lds_bl[CDIM * SA];
    __shared__ float lds_xsqp[BM][8];
    __shared__ float lds_xsq[BM];
    __shared__ float lds_wsq[CDIM];

    const int tid = threadIdx.x;
    const int row_base = blockIdx.x * BM;

    // X staging: thread -> rows {rsub, rsub+32}, float4 chunk k4
    const int rsub = tid >> 3;
    const int k4   = tid & 7;
    const int kofs = k4 * 4;
    // B staging: thread -> class cB, 8-elem segment segB
    const int cB   = tid >> 2;
    const int segB = (tid & 3) * 8;
    // compute assignment
    const int wave = tid >> 6;
    const int lane = tid & 63;
    const int quad = lane >> 4;
    const int l15  = lane & 15;

    if (tid < CDIM) lds_wsq[tid] = wsq_g[tid];

    float p0 = 0.f, p1 = 0.f;
    f32x4 acc[4];
#pragma unroll
    for (int n = 0; n < 4; n++) acc[n] = (f32x4){0.f, 0.f, 0.f, 0.f};

    const float* Xp0 = X + (size_t)(row_base + rsub) * FDIM;
    const float* Xp1 = Xp0 + (size_t)32 * FDIM;
    const unsigned short* Bhp = Bh + (size_t)cB * FDIM + segB;
    const unsigned short* Blp = Bl + (size_t)cB * FDIM + segB;

    for (int kk = 0; kk < FDIM; kk += BK) {
        float4 rv = *(const float4*)(r + kk + kofs);
        rv.x = fmaxf(rv.x, EPS_R); rv.y = fmaxf(rv.y, EPS_R);
        rv.z = fmaxf(rv.z, EPS_R); rv.w = fmaxf(rv.w, EPS_R);
        const float4 xv0 = *(const float4*)(Xp0 + kk + kofs);
        const float4 xv1 = *(const float4*)(Xp1 + kk + kofs);
        const uint4 bhv = *(const uint4*)(Bhp + kk);
        const uint4 blv = *(const uint4*)(Blp + kk);

        p0 += rv.x * xv0.x * xv0.x + rv.y * xv0.y * xv0.y
            + rv.z * xv0.z * xv0.z + rv.w * xv0.w * xv0.w;
        p1 += rv.x * xv1.x * xv1.x + rv.y * xv1.y * xv1.y
            + rv.z * xv1.z * xv1.z + rv.w * xv1.w * xv1.w;

        unsigned h0, l0, h1, l1;
        split2(xv0.x * XSCALE, xv0.y * XSCALE, h0, l0);
        split2(xv0.z * XSCALE, xv0.w * XSCALE, h1, l1);
        *(uint2*)&lds_ah[rsub * SA + kofs] = make_uint2(h0, h1);
        *(uint2*)&lds_al[rsub * SA + kofs] = make_uint2(l0, l1);
        split2(xv1.x * XSCALE, xv1.y * XSCALE, h0, l0);
        split2(xv1.z * XSCALE, xv1.w * XSCALE, h1, l1);
        *(uint2*)&lds_ah[(rsub + 32) * SA + kofs] = make_uint2(h0, h1);
        *(uint2*)&lds_al[(rsub + 32) * SA + kofs] = make_uint2(l0, l1);

        *(uint4*)&lds_bh[cB * SA + segB] = bhv;
        *(uint4*)&lds_bl[cB * SA + segB] = blv;

        __syncthreads();

        const half8 ah = *(const half8*)&lds_ah[(wave * 16 + l15) * SA + quad * 8];
        const half8 al = *(const half8*)&lds_al[(wave * 16 + l15) * SA + quad * 8];
#pragma unroll
        for (int n = 0; n < 4; n++) {
            const half8 bhf = *(const half8*)&lds_bh[(n * 16 + l15) * SA + quad * 8];
            const half8 blf = *(const half8*)&lds_bl[(n * 16 + l15) * SA + quad * 8];
            acc[n] = __builtin_amdgcn_mfma_f32_16x16x32_f16(ah, bhf, acc[n], 0, 0, 0);
            acc[n] = __builtin_amdgcn_mfma_f32_16x16x32_f16(ah, blf, acc[n], 0, 0, 0);
            acc[n] = __builtin_amdgcn_mfma_f32_16x16x32_f16(al, bhf, acc[n], 0, 0, 0);
        }
        __syncthreads();
    }

    // reduce x_sq partials
    lds_xsqp[rsub][k4]      = p0;
    lds_xsqp[rsub + 32][k4] = p1;
    __syncthreads();
    if (tid < BM) {
        float sx = 0.f;
#pragma unroll
        for (int j = 0; j < 8; j++) sx += lds_xsqp[tid][j];
        lds_xsq[tid] = sx;
    }
    __syncthreads();

    // epilogue: d = x_sq + w_sq - 2*cross ; C/D layout: col=lane&15, row=quad*4+reg
    float dd[4][4];
#pragma unroll
    for (int n = 0; n < 4; n++) {
#pragma unroll
        for (int rr = 0; rr < 4; rr++) {
            const int m = wave * 16 + quad * 4 + rr;
            const int c = n * 16 + l15;
            const float d = lds_xsq[m] + lds_wsq[c] - acc[n][rr] * DESCALE;
            dd[n][rr] = d;
            dists[(size_t)(row_base + m) * CDIM + c] = d;
        }
    }

    // argmin over 64 classes per row (lowest-index tie-break, matching jnp.argmin)
#pragma unroll
    for (int rr = 0; rr < 4; rr++) {
        float bv = dd[0][rr];
        int   bi = l15;
#pragma unroll
        for (int n = 1; n < 4; n++) {
            const float v = dd[n][rr];
            const int  ci = n * 16 + l15;
            if (v < bv || (v == bv && ci < bi)) { bv = v; bi = ci; }
        }
#pragma unroll
        for (int mask = 1; mask < 16; mask <<= 1) {
            const float ov = __shfl_xor(bv, mask);
            const int   oi = __shfl_xor(bi, mask);
            if (ov < bv || (ov == bv && oi < bi)) { bv = ov; bi = oi; }
        }
        if (l15 == 0) {
            const int m = wave * 16 + quad * 4 + rr;
            preds[row_base + m] = (float)bi;
        }
    }
}

extern "C" void kernel_launch(void* const* d_in, const int* in_sizes, int n_in,
                              void* d_out, int out_size, void* d_ws, size_t ws_size,
                              hipStream_t stream) {
    const float* X = (const float*)d_in[0];
    const float* W = (const float*)d_in[1];
    const float* r = (const float*)d_in[2];
    float* dists = (float*)d_out;
    float* preds = dists + (size_t)NROWS * CDIM;

    unsigned short* Bh = (unsigned short*)d_ws;                 // 64*2048 fp16 = 256 KB
    unsigned short* Bl = Bh + (size_t)CDIM * FDIM;              // 256 KB
    float* wsq = (float*)(Bl + (size_t)CDIM * FDIM);            // 256 B

    gmlvq_prep<<<dim3(CDIM), dim3(256), 0, stream>>>(W, r, Bh, Bl, wsq);
    gmlvq_main<<<dim3(NROWS / BM), dim3(256), 0, stream>>>(X, r, Bh, Bl, wsq, dists, preds);
}

// Round 3
// 389.153 us; speedup vs baseline: 1.0056x; 1.0056x over previous
//
#include <hip/hip_runtime.h>

#define NROWS 32768
#define FDIM  2048
#define CDIM  64
#define BM    64
#define BK    32
#define NCH   (FDIM / BK)   // 64 chunks
#define SA    40            // padded LDS row stride (halfs); 2-way bank alias = free
#define EPS_R 1e-6f
#define WSCALE 1024.0f
#define DESCALE (2.0f / WSCALE)

typedef __attribute__((ext_vector_type(8))) _Float16 half8;
typedef __attribute__((ext_vector_type(4))) float    f32x4;

__device__ __forceinline__ unsigned packh(_Float16 a, _Float16 b) {
    return (unsigned)__builtin_bit_cast(unsigned short, a) |
           ((unsigned)__builtin_bit_cast(unsigned short, b) << 16);
}

__device__ __forceinline__ void split2(float a, float b, unsigned& hi, unsigned& lo) {
    _Float16 ha = (_Float16)a, hb = (_Float16)b;
    _Float16 la = (_Float16)(a - (float)ha), lb = (_Float16)(b - (float)hb);
    hi = packh(ha, hb);
    lo = packh(la, lb);
}

// ---- prep: Bh/Bl = fp16 split of (W*rc)*WSCALE, plus w_sq and clipped rc ----
__global__ __launch_bounds__(256) void gmlvq_prep(
    const float* __restrict__ W, const float* __restrict__ r,
    unsigned short* __restrict__ Bh, unsigned short* __restrict__ Bl,
    float* __restrict__ wsq, float* __restrict__ rc_out) {
    const int c = blockIdx.x;
    const int tid = threadIdx.x;
    const int f0 = tid * 8;                       // 256*8 = 2048 exactly

    const float* Wp = W + (size_t)c * FDIM + f0;
    float4 w0 = *(const float4*)Wp;
    float4 w1 = *(const float4*)(Wp + 4);
    float4 r0 = *(const float4*)(r + f0);
    float4 r1 = *(const float4*)(r + f0 + 4);
    r0.x = fmaxf(r0.x, EPS_R); r0.y = fmaxf(r0.y, EPS_R);
    r0.z = fmaxf(r0.z, EPS_R); r0.w = fmaxf(r0.w, EPS_R);
    r1.x = fmaxf(r1.x, EPS_R); r1.y = fmaxf(r1.y, EPS_R);
    r1.z = fmaxf(r1.z, EPS_R); r1.w = fmaxf(r1.w, EPS_R);

    if (c == 0) {
        *(float4*)(rc_out + f0) = r0;
        *(float4*)(rc_out + f0 + 4) = r1;
    }

    float rw0 = r0.x * w0.x, rw1 = r0.y * w0.y, rw2 = r0.z * w0.z, rw3 = r0.w * w0.w;
    float rw4 = r1.x * w1.x, rw5 = r1.y * w1.y, rw6 = r1.z * w1.z, rw7 = r1.w * w1.w;

    float part = rw0 * w0.x + rw1 * w0.y + rw2 * w0.z + rw3 * w0.w
               + rw4 * w1.x + rw5 * w1.y + rw6 * w1.z + rw7 * w1.w;

    unsigned h01, l01, h23, l23, h45, l45, h67, l67;
    split2(rw0 * WSCALE, rw1 * WSCALE, h01, l01);
    split2(rw2 * WSCALE, rw3 * WSCALE, h23, l23);
    split2(rw4 * WSCALE, rw5 * WSCALE, h45, l45);
    split2(rw6 * WSCALE, rw7 * WSCALE, h67, l67);

    *(uint4*)(Bh + (size_t)c * FDIM + f0) = make_uint4(h01, h23, h45, h67);
    *(uint4*)(Bl + (size_t)c * FDIM + f0) = make_uint4(l01, l23, l45, l67);

#pragma unroll
    for (int m = 32; m; m >>= 1) part += __shfl_xor(part, m);
    __shared__ float red[4];
    if ((tid & 63) == 0) red[tid >> 6] = part;
    __syncthreads();
    if (tid == 0) wsq[c] = (red[0] + red[1]) + (red[2] + red[3]);
}

// ---- main: A direct global->reg->frag split; B via single-barrier LDS dbuf ----
__global__ __launch_bounds__(256, 3) void gmlvq_main(
    const float* __restrict__ X, const float* __restrict__ rc,
    const unsigned short* __restrict__ Bh, const unsigned short* __restrict__ Bl,
    const float* __restrict__ wsq_g,
    float* __restrict__ dists, float* __restrict__ preds) {

    __shared__ __align__(16) unsigned short lds_bh[2][CDIM * SA];
    __shared__ __align__(16) unsigned short lds_bl[2][CDIM * SA];
    __shared__ float lds_xsq[BM];
    __shared__ float lds_wsq[CDIM];

    const int tid  = threadIdx.x;
    const int wave = tid >> 6;
    const int lane = tid & 63;
    const int quad = lane >> 4;
    const int l15  = lane & 15;
    const int row_base = blockIdx.x * BM;
    const int cB   = tid >> 2;          // B staging: class per thread-group-of-4
    const int segB = (tid & 3) * 8;     // 8-half segment

    if (tid < CDIM) lds_wsq[tid] = wsq_g[tid];

    const float* Ap = X + (size_t)(row_base + wave * 16 + l15) * FDIM + quad * 8;
    const float* Rp = rc + quad * 8;
    const unsigned short* Bhp = Bh + (size_t)cB * FDIM + segB;
    const unsigned short* Blp = Bl + (size_t)cB * FDIM + segB;

    // prologue: B0 -> LDS buf0; B1 -> regs; A0/rc0 -> regs
    uint4 b0h = *(const uint4*)(Bhp);
    uint4 b0l = *(const uint4*)(Blp);
    *(uint4*)&lds_bh[0][cB * SA + segB] = b0h;
    *(uint4*)&lds_bl[0][cB * SA + segB] = b0l;
    uint4 bnh = *(const uint4*)(Bhp + BK);
    uint4 bnl = *(const uint4*)(Blp + BK);

    float4 a0 = *(const float4*)(Ap);
    float4 a1 = *(const float4*)(Ap + 4);
    float4 r0 = *(const float4*)(Rp);
    float4 r1 = *(const float4*)(Rp + 4);

    float p = 0.f;     // per-lane x_sq partial (row = wave*16+l15, k in quad's slices)
    f32x4 acc[4];
#pragma unroll
    for (int n = 0; n < 4; n++) acc[n] = (f32x4){0.f, 0.f, 0.f, 0.f};

#pragma unroll 2
    for (int c = 0; c < NCH; c++) {
        __syncthreads();                       // buf[c&1] ready

        const int kn = ((c + 1) & (NCH - 1)) * BK;   // next A/rc chunk (ring; wrap harmless)
        const int kf = ((c + 2) & (NCH - 1)) * BK;   // far B chunk
        const float4 a0n = *(const float4*)(Ap + kn);
        const float4 a1n = *(const float4*)(Ap + kn + 4);
        const float4 r0n = *(const float4*)(Rp + kn);
        const float4 r1n = *(const float4*)(Rp + kn + 4);
        const uint4  bfh = *(const uint4*)(Bhp + kf);
        const uint4  bfl = *(const uint4*)(Blp + kf);

        // split current A regs into fp16 hi/lo frags + accumulate r*x^2 in fp32
        half8 ah, al;
        {
            const float va[8] = {a0.x, a0.y, a0.z, a0.w, a1.x, a1.y, a1.z, a1.w};
            const float vr[8] = {r0.x, r0.y, r0.z, r0.w, r1.x, r1.y, r1.z, r1.w};
#pragma unroll
            for (int j = 0; j < 8; j++) {
                const float v = va[j];
                const _Float16 h = (_Float16)v;
                ah[j] = h;
                al[j] = (_Float16)(v - (float)h);
                p += vr[j] * v * v;
            }
        }

        const int bb = c & 1;
#pragma unroll
        for (int n = 0; n < 4; n++) {
            const half8 bhf = *(const half8*)&lds_bh[bb][(n * 16 + l15) * SA + quad * 8];
            const half8 blf = *(const half8*)&lds_bl[bb][(n * 16 + l15) * SA + quad * 8];
            acc[n] = __builtin_amdgcn_mfma_f32_16x16x32_f16(ah, bhf, acc[n], 0, 0, 0);
            acc[n] = __builtin_amdgcn_mfma_f32_16x16x32_f16(ah, blf, acc[n], 0, 0, 0);
            acc[n] = __builtin_amdgcn_mfma_f32_16x16x32_f16(al, bhf, acc[n], 0, 0, 0);
        }

        // stage next B chunk into the other buffer (safe: last read of that
        // buffer was before the barrier at the top of this iteration)
        *(uint4*)&lds_bh[bb ^ 1][cB * SA + segB] = bnh;
        *(uint4*)&lds_bl[bb ^ 1][cB * SA + segB] = bnl;

        bnh = bfh; bnl = bfl;
        a0 = a0n; a1 = a1n; r0 = r0n; r1 = r1n;
    }

    // x_sq: reduce across the 4 quads holding the same row
    p += __shfl_xor(p, 16);
    p += __shfl_xor(p, 32);
    if (quad == 0) lds_xsq[wave * 16 + l15] = p;
    __syncthreads();

    // epilogue: d = x_sq + w_sq - 2*cross ; C/D layout: col=lane&15, row=quad*4+reg
    float dd[4][4];
#pragma unroll
    for (int n = 0; n < 4; n++) {
#pragma unroll
        for (int rr = 0; rr < 4; rr++) {
            const int m = wave * 16 + quad * 4 + rr;
            const int cc = n * 16 + l15;
            const float d = lds_xsq[m] + lds_wsq[cc] - acc[n][rr] * DESCALE;
            dd[n][rr] = d;
            dists[(size_t)(row_base + m) * CDIM + cc] = d;
        }
    }

    // argmin over 64 classes per row (lowest-index tie-break)
#pragma unroll
    for (int rr = 0; rr < 4; rr++) {
        float bv = dd[0][rr];
        int   bi = l15;
#pragma unroll
        for (int n = 1; n < 4; n++) {
            const float v = dd[n][rr];
            const int  ci = n * 16 + l15;
            if (v < bv || (v == bv && ci < bi)) { bv = v; bi = ci; }
        }
#pragma unroll
        for (int mask = 1; mask < 16; mask <<= 1) {
            const float ov = __shfl_xor(bv, mask);
            const int   oi = __shfl_xor(bi, mask);
            if (ov < bv || (ov == bv && oi < bi)) { bv = ov; bi = oi; }
        }
        if (l15 == 0) {
            const int m = wave * 16 + quad * 4 + rr;
            preds[row_base + m] = (float)bi;
        }
    }
}

extern "C" void kernel_launch(void* const* d_in, const int* in_sizes, int n_in,
                              void* d_out, int out_size, void* d_ws, size_t ws_size,
                              hipStream_t stream) {
    const float* X = (const float*)d_in[0];
    const float* W = (const float*)d_in[1];
    const float* r = (const float*)d_in[2];
    float* dists = (float*)d_out;
    float* preds = dists + (size_t)NROWS * CDIM;

    unsigned short* Bh = (unsigned short*)d_ws;                 // 256 KB
    unsigned short* Bl = Bh + (size_t)CDIM * FDIM;              // 256 KB
    float* wsq   = (float*)(Bl + (size_t)CDIM * FDIM);          // 256 B
    float* rc_ws = wsq + CDIM;                                  // 8 KB

    gmlvq_prep<<<dim3(CDIM), dim3(256), 0, stream>>>(W, r, Bh, Bl, wsq, rc_ws);
    gmlvq_main<<<dim3(NROWS / BM), dim3(256), 0, stream>>>(X, rc_ws, Bh, Bl, wsq, dists, preds);
}